// Round 7
// baseline (12.795 us; speedup 1.0000x reference)
//
#include <hip/hip_runtime.h>
#include <hip/hip_fp16.h>

// LocalAttention: B=1, H=8, S=2048, D=64, window +/-64 (129 positions), fp32 io.
// 2-blocks/CU split-k MFMA design. 512 blocks (2/CU), 256 threads (4 waves), QB=32.
// Waves: t = w&1 (q-tile), half = w>>1 (k-range: chunks 0-2 / 3-4 of 160 rows).
// Per 32-row chunk: QK (2 tiles x 2 MFMA) -> exp -> wave-local P strip -> PV
// (4 dtiles x 1 MFMA); P ordering is same-wave DS program order.
// K row-major f16 LDS (stride 72h), V^T f16 LDS (384B stride + 16B XOR swizzle),
// Q frags from global. h = blockIdx.x & 7 keeps each head on one XCD's L2.
// Split-k combine through 10KB LDS + one barrier.

#define SEQ 2048
#define NH 8
#define QB 32
#define ROWS 160
#define KSTR 72          // Kl stride in halfs (144 B)
#define PSTR 40          // P strip stride in halfs (80 B)

typedef _Float16 f16x8 __attribute__((ext_vector_type(8)));
typedef float    f32x4 __attribute__((ext_vector_type(4)));

static __device__ __forceinline__ ushort4 pack4(float4 f, float s) {
    union { _Float16 h[4]; ushort4 u; } p;
    p.h[0] = (_Float16)(f.x * s);
    p.h[1] = (_Float16)(f.y * s);
    p.h[2] = (_Float16)(f.z * s);
    p.h[3] = (_Float16)(f.w * s);
    return p.u;
}

__global__ __launch_bounds__(256, 2) void local_attn(
    const float* __restrict__ q,
    const float* __restrict__ k,
    const float* __restrict__ v,
    float* __restrict__ out)
{
    __shared__ __align__(16) _Float16      Kl[ROWS * KSTR];   // 23040 B
    __shared__ __align__(16) unsigned char VtB[64 * 384];     // 24576 B
    __shared__ __align__(16) _Float16      Pm[4][16 * PSTR];  //  5120 B
    __shared__ __align__(16) float         Cmb[2][64][20];    // 10240 B

    const int tid  = threadIdx.x;
    const int lane = tid & 63;
    const int w    = tid >> 6;           // 0..3
    const int t    = w & 1;              // q-tile 0..1
    const int half = w >> 1;             // 0: chunks 0-2, 1: chunks 3-4
    const int l15  = lane & 15;
    const int l4   = lane >> 4;
    const int bx   = blockIdx.x;
    const int h     = bx & 7;            // head == XCD (round-robin dispatch)
    const int qbase = (bx >> 3) * QB;

    const float* kh = k + (size_t)h * SEQ * 64;
    const float* vh = v + (size_t)h * SEQ * 64;
    const float* qh = q + (size_t)h * SEQ * 64;

    // ---- Q A-fragments straight from global (1/sqrt(64)=0.125 folded in)
    const float* qrow = qh + (size_t)(qbase + t * 16 + l15) * 64 + l4 * 8;
    float4 q0 = *(const float4*)(qrow);
    float4 q1 = *(const float4*)(qrow + 4);
    float4 q2 = *(const float4*)(qrow + 32);
    float4 q3 = *(const float4*)(qrow + 36);
    union uf { f16x8 v; _Float16 hh[8]; };
    uf A0, A1;
    A0.hh[0] = (_Float16)(q0.x * 0.125f); A0.hh[1] = (_Float16)(q0.y * 0.125f);
    A0.hh[2] = (_Float16)(q0.z * 0.125f); A0.hh[3] = (_Float16)(q0.w * 0.125f);
    A0.hh[4] = (_Float16)(q1.x * 0.125f); A0.hh[5] = (_Float16)(q1.y * 0.125f);
    A0.hh[6] = (_Float16)(q1.z * 0.125f); A0.hh[7] = (_Float16)(q1.w * 0.125f);
    A1.hh[0] = (_Float16)(q2.x * 0.125f); A1.hh[1] = (_Float16)(q2.y * 0.125f);
    A1.hh[2] = (_Float16)(q2.z * 0.125f); A1.hh[3] = (_Float16)(q2.w * 0.125f);
    A1.hh[4] = (_Float16)(q3.x * 0.125f); A1.hh[5] = (_Float16)(q3.y * 0.125f);
    A1.hh[6] = (_Float16)(q3.z * 0.125f); A1.hh[7] = (_Float16)(q3.w * 0.125f);

    // ---- stage K (row-major f16) and V^T (swizzled); zero-fill OOB rows
    {
        const int d4  = (tid & 15) << 2;     // fixed dims 0,4,...,60
        const int lr0 = tid >> 4;            // 0..15; rows advance by 16/iter
        #pragma unroll
        for (int it = 0; it < 10; ++it) {
            const int lr = lr0 + it * 16;    // 0..159
            const int g  = qbase - 64 + lr;
            float4 kv4 = make_float4(0.f, 0.f, 0.f, 0.f);
            float4 vv4 = make_float4(0.f, 0.f, 0.f, 0.f);
            if (g >= 0 && g < SEQ) {
                kv4 = *(const float4*)(kh + (size_t)g * 64 + d4);
                vv4 = *(const float4*)(vh + (size_t)g * 64 + d4);
            }
            *(ushort4*)&Kl[lr * KSTR + d4] = pack4(kv4, 1.0f);
            float vs[4] = {vv4.x, vv4.y, vv4.z, vv4.w};
            #pragma unroll
            for (int i2 = 0; i2 < 4; ++i2) {
                int d = d4 + i2;
                int u = (lr >> 3) ^ (d & 7);
                *(_Float16*)&VtB[d * 384 + (u << 4) + (lr & 7) * 2] = (_Float16)vs[i2];
            }
        }
    }
    __syncthreads();

    // ---- main loop: wave-private chunks (half0: rows 0-95, half1: rows 96-159)
    _Float16* Pw = Pm[w];
    float rsum[4] = {0.f, 0.f, 0.f, 0.f};
    f32x4 o[4];
    #pragma unroll
    for (int dt = 0; dt < 4; ++dt) o[dt] = (f32x4){0.f, 0.f, 0.f, 0.f};

#define DO_CHUNK(R0)                                                          \
    {                                                                         \
        const int r0 = (R0);                                                  \
        _Pragma("unroll")                                                     \
        for (int t2 = 0; t2 < 2; ++t2) {                                      \
            const int r = r0 + t2 * 16 + l15;                                 \
            f16x8 b0 = *(const f16x8*)&Kl[r * KSTR + l4 * 8];                 \
            f16x8 b1 = *(const f16x8*)&Kl[r * KSTR + 32 + l4 * 8];            \
            f32x4 cacc = {0.f, 0.f, 0.f, 0.f};                                \
            cacc = __builtin_amdgcn_mfma_f32_16x16x32_f16(A0.v, b0, cacc, 0, 0, 0); \
            cacc = __builtin_amdgcn_mfma_f32_16x16x32_f16(A1.v, b1, cacc, 0, 0, 0); \
            const int g  = qbase - 64 + r;                                    \
            const bool gv = (g >= 0) & (g < SEQ);                             \
            _Pragma("unroll")                                                 \
            for (int j = 0; j < 4; ++j) {                                     \
                const int qg = qbase + t * 16 + l4 * 4 + j;                   \
                const bool valid = gv && (g >= qg - 64) && (g <= qg + 64);    \
                const float e = valid ? __expf(cacc[j]) : 0.f;                \
                rsum[j] += e;                                                 \
                Pw[(l4 * 4 + j) * PSTR + t2 * 16 + l15] = (_Float16)e;        \
            }                                                                 \
        }                                                                     \
        asm volatile("s_waitcnt lgkmcnt(0)" ::: "memory");                    \
        f16x8 a = *(const f16x8*)&Pw[l15 * PSTR + l4 * 8];                    \
        _Pragma("unroll")                                                     \
        for (int dt = 0; dt < 4; ++dt) {                                      \
            const int dim = dt * 16 + l15;                                    \
            const int u   = ((r0 + l4 * 8) >> 3) ^ (dim & 7);                 \
            f16x8 bb = *(const f16x8*)&VtB[dim * 384 + (u << 4)];             \
            o[dt] = __builtin_amdgcn_mfma_f32_16x16x32_f16(a, bb, o[dt], 0, 0, 0); \
        }                                                                     \
    }

    if (half == 0) {
        DO_CHUNK(0)
        DO_CHUNK(32)
        DO_CHUNK(64)
    } else {
        DO_CHUNK(96)
        DO_CHUNK(128)
    }
#undef DO_CHUNK

    // ---- split-k combine: half-1 waves publish partials; half-0 waves merge
    if (half == 1) {
        #pragma unroll
        for (int dt = 0; dt < 4; ++dt)
            *(f32x4*)&Cmb[t][lane][dt * 4] = o[dt];
        f32x4 pr = {rsum[0], rsum[1], rsum[2], rsum[3]};
        *(f32x4*)&Cmb[t][lane][16] = pr;
    }
    __syncthreads();
    if (half == 0) {
        #pragma unroll
        for (int dt = 0; dt < 4; ++dt) {
            f32x4 p = *(const f32x4*)&Cmb[t][lane][dt * 4];
            o[dt] += p;
        }
        f32x4 pr = *(const f32x4*)&Cmb[t][lane][16];

        #pragma unroll
        for (int j = 0; j < 4; ++j) {
            float l = rsum[j] + pr[j];
            l += __shfl_xor(l, 1, 64);
            l += __shfl_xor(l, 2, 64);
            l += __shfl_xor(l, 4, 64);
            l += __shfl_xor(l, 8, 64);
            const float inv = 1.0f / l;
            const int qg = qbase + t * 16 + l4 * 4 + j;
            #pragma unroll
            for (int dt = 0; dt < 4; ++dt)
                out[((size_t)h * SEQ + qg) * 64 + dt * 16 + l15] = o[dt][j] * inv;
        }
    }
}

extern "C" void kernel_launch(void* const* d_in, const int* in_sizes, int n_in,
                              void* d_out, int out_size, void* d_ws, size_t ws_size,
                              hipStream_t stream)
{
    const float* q = (const float*)d_in[0];
    const float* k = (const float*)d_in[1];
    const float* v = (const float*)d_in[2];
    float* out = (float*)d_out;

    // 512 blocks = 2 per CU; low 3 bits = head -> one head per XCD (L2 locality)
    local_attn<<<512, 256, 0, stream>>>(q, k, v, out);
}